// Round 17
// baseline (216.920 us; speedup 1.0000x reference)
//
#include <hip/hip_runtime.h>
#include <hip/hip_bf16.h>

#define N_NODES 100000
#define N_EDGES 1600000
#define NEG_SLOPE 0.2f

// --- bucket sort geometry ---
#define BUCK_SHIFT 7
#define NBUCK ((N_NODES + 127) >> BUCK_SHIFT)     // 782 buckets of 128 nodes
#define B1 128                                    // blocks in hist/scatter stages
                                                  // (16-entry runs = 64B lines, 1 writer/line)
#define CHUNK ((N_EDGES + B1 - 1) / B1)           // 12500 edges per block chunk

// --- generic scan geometry (for NBUCK*B1 = 100096 elements) ---
#define SCAN_ITEMS 4
#define SCAN_BLK 256
#define SCAN_CHUNK (SCAN_BLK * SCAN_ITEMS)        // 1024
#define NSCAN (NBUCK * B1)                        // 100096
#define SCAN_NB ((NSCAN + SCAN_CHUNK - 1) / SCAN_CHUNK)  // 98

typedef _Float16 f16;
typedef _Float16 f16x8 __attribute__((ext_vector_type(8)));
typedef _Float16 f16x2 __attribute__((ext_vector_type(2)));
typedef float f32x4 __attribute__((ext_vector_type(4)));
typedef float f32x2v __attribute__((ext_vector_type(2)));

// ---------------------------------------------------------------------------
// Edge dtype probe (int64 reference vs possible int32 delivery)
// ---------------------------------------------------------------------------
__device__ __forceinline__ bool edges_are_i64(const void* p) {
    const unsigned long long* q = (const unsigned long long*)p;
    bool ok = true;
#pragma unroll
    for (int i = 0; i < 8; i++)
        if (q[i] >= (unsigned long long)N_NODES) ok = false;
    return ok;
}
__device__ __forceinline__ int edge_src(const void* ei, int j, bool i64) {
    return i64 ? (int)((const long long*)ei)[j] : ((const int*)ei)[j];
}
__device__ __forceinline__ int edge_dst(const void* ei, int j, bool i64) {
    return i64 ? (int)((const long long*)ei)[N_EDGES + j] : ((const int*)ei)[N_EDGES + j];
}

// fp8 quad accumulate: 4 fp8 channels from one int, weighted into f32x4
__device__ __forceinline__ void acc4(f32x4& a, float w, int u) {
    f32x2v p0 = __builtin_amdgcn_cvt_pk_f32_fp8(u, false);
    f32x2v p1 = __builtin_amdgcn_cvt_pk_f32_fp8(u, true);
    a[0] = fmaf(w, p0[0], a[0]);
    a[1] = fmaf(w, p0[1], a[1]);
    a[2] = fmaf(w, p1[0], a[2]);
    a[3] = fmaf(w, p1[1], a[3]);
}

// ---------------------------------------------------------------------------
// CSR stage 1: per-(bucket, block) histogram via LDS atomics only.
// ---------------------------------------------------------------------------
__global__ __launch_bounds__(256) void bhist_k(const void* __restrict__ ei,
                                               int* __restrict__ bh) {
    __shared__ int hist[NBUCK];
    bool i64 = edges_are_i64(ei);
    int bl = blockIdx.x, t = threadIdx.x;
    for (int i = t; i < NBUCK; i += 256) hist[i] = 0;
    __syncthreads();
    int lo = bl * CHUNK, hi = min(lo + CHUNK, N_EDGES);
    for (int j = lo + t; j < hi; j += 256)
        atomicAdd(&hist[edge_dst(ei, j, i64) >> BUCK_SHIFT], 1);
    __syncthreads();
    for (int i = t; i < NBUCK; i += 256) bh[i * B1 + bl] = hist[i];
}

// ---------------------------------------------------------------------------
// Generic exclusive scan, n elements. Block sums left UNAPPLIED (consumers
// add bsum[idx / SCAN_CHUNK] themselves -- saves the scan3 pass).
// ---------------------------------------------------------------------------
__global__ __launch_bounds__(SCAN_BLK) void scan1_k(const int* __restrict__ in,
                                                    int* __restrict__ outp,
                                                    int* __restrict__ bsum, int n) {
    __shared__ int lds[SCAN_BLK];
    int t = threadIdx.x, b = blockIdx.x;
    int base = b * SCAN_CHUNK + t * SCAN_ITEMS;
    int v[SCAN_ITEMS];
    int s = 0;
#pragma unroll
    for (int i = 0; i < SCAN_ITEMS; i++) {
        v[i] = (base + i < n) ? in[base + i] : 0;
        s += v[i];
    }
    lds[t] = s;
    __syncthreads();
    for (int o = 1; o < SCAN_BLK; o <<= 1) {
        int x = (t >= o) ? lds[t - o] : 0;
        __syncthreads();
        lds[t] += x;
        __syncthreads();
    }
    if (t == SCAN_BLK - 1) bsum[b] = lds[t];
    int run = lds[t] - s;
#pragma unroll
    for (int i = 0; i < SCAN_ITEMS; i++) {
        if (base + i < n) outp[base + i] = run;
        run += v[i];
    }
}

__global__ __launch_bounds__(256) void scan2_k(int* __restrict__ bsum, int nb) {
    __shared__ int lds[256];
    int t = threadIdx.x;
    int v = (t < nb) ? bsum[t] : 0;
    lds[t] = v;
    __syncthreads();
    for (int o = 1; o < 256; o <<= 1) {
        int x = (t >= o) ? lds[t - o] : 0;
        __syncthreads();
        lds[t] += x;
        __syncthreads();
    }
    if (t < nb) bsum[t] = lds[t] - v;
}

// ---------------------------------------------------------------------------
// CSR stage 2: scatter edges into bucket-grouped packed (src<<7 | dlocal).
// Cursor init folds in the block-sum (fused scan3).
// ---------------------------------------------------------------------------
__global__ __launch_bounds__(256) void bscatter_k(const void* __restrict__ ei,
                                                  const int* __restrict__ bh,
                                                  const int* __restrict__ bsum,
                                                  int* __restrict__ be) {
    __shared__ int cur[NBUCK];
    bool i64 = edges_are_i64(ei);
    int bl = blockIdx.x, t = threadIdx.x;
    for (int i = t; i < NBUCK; i += 256) {
        int idx = i * B1 + bl;
        cur[i] = bh[idx] + bsum[idx / SCAN_CHUNK];
    }
    __syncthreads();
    int lo = bl * CHUNK, hi = min(lo + CHUNK, N_EDGES);
    for (int j = lo + t; j < hi; j += 256) {
        int d = edge_dst(ei, j, i64);
        int sr = edge_src(ei, j, i64);
        int pos = atomicAdd(&cur[d >> BUCK_SHIFT], 1);
        be[pos] = (sr << BUCK_SHIFT) | (d & 127);
    }
}

// ---------------------------------------------------------------------------
// CSR stage 3: one block per bucket -> rp + csrc. No global atomics.
// ---------------------------------------------------------------------------
__global__ __launch_bounds__(256) void bcsr_k(const int* __restrict__ bh,
                                              const int* __restrict__ bsum,
                                              const int* __restrict__ be,
                                              int* __restrict__ rp,
                                              int* __restrict__ csrc) {
    __shared__ int cnt[128];
    __shared__ int pre[128];
    int b = blockIdx.x, t = threadIdx.x;
    int bi = b * B1;
    int beg = bh[bi] + bsum[bi / SCAN_CHUNK];
    int end = N_EDGES;
    if (b != NBUCK - 1) {
        int bj = (b + 1) * B1;
        end = bh[bj] + bsum[bj / SCAN_CHUNK];
    }
    if (t < 128) cnt[t] = 0;
    __syncthreads();
    for (int j = beg + t; j < end; j += 256)
        atomicAdd(&cnt[be[j] & 127], 1);
    __syncthreads();
    if (t < 128) pre[t] = cnt[t];
    __syncthreads();
    for (int o = 1; o < 128; o <<= 1) {
        int x = 0;
        if (t < 128 && t >= o) x = pre[t - o];
        __syncthreads();
        if (t < 128) pre[t] += x;
        __syncthreads();
    }
    if (t < 128) {
        int node = (b << BUCK_SHIFT) + t;
        int excl = pre[t] - cnt[t];
        if (node < N_NODES) rp[node] = beg + excl;
        cnt[t] = excl;
    }
    if (b == 0 && t == 0) rp[N_NODES] = N_EDGES;
    __syncthreads();
    for (int j = beg + t; j < end; j += 256) {
        int e = be[j];
        int pos = beg + atomicAdd(&cnt[e & 127], 1);
        csrc[pos] = e >> BUCK_SHIFT;
    }
}

// ---------------------------------------------------------------------------
// Pre-shuffle W[K=128 x M=NCT*16] into MFMA B-fragment order
// ---------------------------------------------------------------------------
template <int NCT>
__global__ void cvt_wfrag_k(const float* __restrict__ W, f16* __restrict__ wf) {
    int idx = blockIdx.x * blockDim.x + threadIdx.x;
    if (idx >= 4 * NCT * 512) return;
    int j = idx & 7;
    int lane = (idx >> 3) & 63;
    int ct = (idx >> 9) % NCT;
    int ks = (idx >> 9) / NCT;
    int k = ks * 32 + 8 * (lane >> 4) + j;
    int col = ct * 16 + (lane & 15);
    wf[idx] = (f16)W[k * (NCT * 16) + col];
}

// ---------------------------------------------------------------------------
// MFMA GEMM: H[n x NCT*16] = A[n x 128] @ W. 4 waves x 16 rows per block.
// ---------------------------------------------------------------------------
template <int NCT, typename AT>
__global__ __launch_bounds__(256) void gemm_mfma(const AT* __restrict__ A,
                                                 const f16* __restrict__ wf,
                                                 f16* __restrict__ H, int n) {
    int lane = threadIdx.x & 63;
    int row0 = blockIdx.x * 64 + (threadIdx.x >> 6) * 16;
    int m = lane & 15, g = lane >> 4;
    f32x4 acc[NCT];
#pragma unroll
    for (int ct = 0; ct < NCT; ct++) acc[ct] = (f32x4){0.f, 0.f, 0.f, 0.f};

    int ar = row0 + m;
    if (ar >= n) ar = 0;
    const AT* arow = A + (size_t)ar * 128 + g * 8;
    const f16x8* bp = (const f16x8*)wf;
#pragma unroll
    for (int ks = 0; ks < 4; ks++) {
        f16x8 af;
        if constexpr (sizeof(AT) == 4) {
            const float4* p = (const float4*)(arow + ks * 32);
            float4 a = p[0], b = p[1];
            af[0] = (f16)a.x; af[1] = (f16)a.y; af[2] = (f16)a.z; af[3] = (f16)a.w;
            af[4] = (f16)b.x; af[5] = (f16)b.y; af[6] = (f16)b.z; af[7] = (f16)b.w;
        } else {
            af = *(const f16x8*)(arow + ks * 32);
        }
#pragma unroll
        for (int ct = 0; ct < NCT; ct++) {
            f16x8 bf = bp[(ks * NCT + ct) * 64 + lane];
            acc[ct] = __builtin_amdgcn_mfma_f32_16x16x32_f16(af, bf, acc[ct], 0, 0, 0);
        }
    }
#pragma unroll
    for (int ct = 0; ct < NCT; ct++)
#pragma unroll
        for (int r = 0; r < 4; r++) {
            int orow = row0 + g * 4 + r;
            if (orow < n) H[(size_t)orow * (NCT * 16) + ct * 16 + m] = (f16)acc[ct][r];
        }
}

// ---------------------------------------------------------------------------
// Per-node attention half-scores + fp8(e4m3) encode of the feature rows.
// ---------------------------------------------------------------------------
template <int HEADS, int CH>
__global__ void att_scores(const f16* __restrict__ H, const float* __restrict__ att_s,
                           const float* __restrict__ att_d, float* __restrict__ a_s,
                           float* __restrict__ a_d, unsigned char* __restrict__ h8,
                           int n) {
    int idx = blockIdx.x * blockDim.x + threadIdx.x;
    if (idx >= n * HEADS) return;
    int node = idx / HEADS;
    int h = idx - node * HEADS;
    const f16x8* hp = (const f16x8*)(H + (size_t)node * (HEADS * CH) + h * CH);
    float vals[CH];
    float s = 0.f, d = 0.f;
#pragma unroll
    for (int c8 = 0; c8 < CH / 8; c8++) {
        f16x8 v = hp[c8];
#pragma unroll
        for (int j = 0; j < 8; j++) {
            float x = (float)v[j];
            vals[c8 * 8 + j] = x;
            s = fmaf(x, att_s[h * CH + c8 * 8 + j], s);
            d = fmaf(x, att_d[h * CH + c8 * 8 + j], d);
        }
    }
    a_s[idx] = s;
    a_d[idx] = d;

    int4* dst = (int4*)(h8 + (size_t)node * (HEADS * CH) + h * CH);
#pragma unroll
    for (int t = 0; t < CH / 16; t++) {
        int w[4];
#pragma unroll
        for (int q = 0; q < 4; q++) {
            int u = __builtin_amdgcn_cvt_pk_fp8_f32(vals[t * 16 + 4 * q],
                                                    vals[t * 16 + 4 * q + 1], 0, false);
            u = __builtin_amdgcn_cvt_pk_fp8_f32(vals[t * 16 + 4 * q + 2],
                                                vals[t * 16 + 4 * q + 3], u, true);
            w[q] = u;
        }
        dst[t] = make_int4(w[0], w[1], w[2], w[3]);
    }
}

// ---------------------------------------------------------------------------
// Layer 1 fused aggregation, software-pipelined, 16-edge chunks:
//   - next chunk's csrc (two slots) preloaded during current chunk
//   - 16 h8 gathers issue (readlane addresses) before the two score exps.
// Lane roles: phase 1 (eidx=lane&7, head=lane>>3) two exps/lane;
// phase 2 weight via static ds_swizzle src=(l&0x38)|K, channels [2l,2l+1].
// ---------------------------------------------------------------------------
__global__ __launch_bounds__(256) void aggr1_k(const int* __restrict__ rp,
                                               const int* __restrict__ csrc,
                                               const float* __restrict__ a_s,
                                               const float* __restrict__ a_d,
                                               const unsigned char* __restrict__ h8,
                                               const float* __restrict__ bias,
                                               f16* __restrict__ out) {
    int lane = threadIdx.x & 63;
    int d = blockIdx.x * 4 + (threadIdx.x >> 6);
    if (d >= N_NODES) return;
    int head = lane >> 3;   // head for score AND value phases
    int eidx = lane & 7;    // phase-1 edge slot

    float ed = a_d[d * 8 + head];

    // self loop
    float e0 = a_s[d * 8 + head] + ed;
    e0 = e0 > 0.f ? e0 : NEG_SLOPE * e0;
    float w0 = __expf(e0);
    unsigned short u0 = *(const unsigned short*)(h8 + (size_t)d * 128 + 2 * lane);
    f32x2v v0 = __builtin_amdgcn_cvt_pk_f32_fp8((int)u0, false);
    float den = w0, nx = w0 * v0[0], ny = w0 * v0[1];

    int beg = rp[d], end = rp[d + 1];
    int sA_cur = 0, sB_cur = 0;
    if (beg < end) {
        int eA = beg + eidx;
        int eB = beg + 8 + eidx;
        sA_cur = csrc[eA < end ? eA : end - 1];
        sB_cur = csrc[eB < end ? eB : end - 1];
    }
    for (int cbeg = beg; cbeg < end; cbeg += 16) {
        int sA = sA_cur, sB = sB_cur;
        // prefetch next chunk's csrc (wave-uniform branch)
        if (cbeg + 16 < end) {
            int eA = cbeg + 16 + eidx;
            int eB = cbeg + 24 + eidx;
            sA_cur = csrc[eA < end ? eA : end - 1];
            sB_cur = csrc[eB < end ? eB : end - 1];
        }
        // issue all 16 h8 gathers first (addresses = readlane)
        unsigned short uu0, uu1, uu2, uu3, uu4, uu5, uu6, uu7;
        unsigned short vv0, vv1, vv2, vv3, vv4, vv5, vv6, vv7;
#define A1_LOADA(K)                                                                       \
        {                                                                                 \
            int se = __builtin_amdgcn_readlane(sA, K);                                    \
            uu##K = *(const unsigned short*)(h8 + (size_t)se * 128 + 2 * lane);           \
        }
#define A1_LOADB(K)                                                                       \
        {                                                                                 \
            int se = __builtin_amdgcn_readlane(sB, K);                                    \
            vv##K = *(const unsigned short*)(h8 + (size_t)se * 128 + 2 * lane);           \
        }
        A1_LOADA(0) A1_LOADA(1) A1_LOADA(2) A1_LOADA(3)
        A1_LOADA(4) A1_LOADA(5) A1_LOADA(6) A1_LOADA(7)
        A1_LOADB(0) A1_LOADB(1) A1_LOADB(2) A1_LOADB(3)
        A1_LOADB(4) A1_LOADB(5) A1_LOADB(6) A1_LOADB(7)
#undef A1_LOADA
#undef A1_LOADB
        // two score gathers (parallel with h8 gathers), then exps
        float asA = a_s[sA * 8 + head];
        float asB = a_s[sB * 8 + head];
        float esA = asA + ed;
        esA = esA > 0.f ? esA : NEG_SLOPE * esA;
        float wA = (cbeg + eidx < end) ? __expf(esA) : 0.f;
        float esB = asB + ed;
        esB = esB > 0.f ? esB : NEG_SLOPE * esB;
        float wB = (cbeg + 8 + eidx < end) ? __expf(esB) : 0.f;
        // consume
#define A1_USEA(K)                                                                        \
        {                                                                                 \
            float we = __int_as_float(__builtin_amdgcn_ds_swizzle(                         \
                __float_as_int(wA), ((K) << 5) | 0x18));                                  \
            f32x2v v = __builtin_amdgcn_cvt_pk_f32_fp8((int)uu##K, false);                \
            den += we;                                                                    \
            nx = fmaf(we, v[0], nx);                                                      \
            ny = fmaf(we, v[1], ny);                                                      \
        }
#define A1_USEB(K)                                                                        \
        {                                                                                 \
            float we = __int_as_float(__builtin_amdgcn_ds_swizzle(                         \
                __float_as_int(wB), ((K) << 5) | 0x18));                                  \
            f32x2v v = __builtin_amdgcn_cvt_pk_f32_fp8((int)vv##K, false);                \
            den += we;                                                                    \
            nx = fmaf(we, v[0], nx);                                                      \
            ny = fmaf(we, v[1], ny);                                                      \
        }
        A1_USEA(0) A1_USEA(1) A1_USEA(2) A1_USEA(3)
        A1_USEA(4) A1_USEA(5) A1_USEA(6) A1_USEA(7)
        A1_USEB(0) A1_USEB(1) A1_USEB(2) A1_USEB(3)
        A1_USEB(4) A1_USEB(5) A1_USEB(6) A1_USEB(7)
#undef A1_USEA
#undef A1_USEB
    }
    float inv = 1.f / (den + 1e-16f);
    float2 b = ((const float2*)bias)[lane];
    f16x2 r;
    r[0] = (f16)fmaxf(fmaf(nx, inv, b.x), 0.f);
    r[1] = (f16)fmaxf(fmaf(ny, inv, b.y), 0.f);
    ((f16x2*)out)[(size_t)d * 64 + lane] = r;
}

// ---------------------------------------------------------------------------
// Layer 2 fused aggregation + bias + log_softmax, software-pipelined,
// 16-edge chunks. lane = (edge slot j=lane>>3, channel octet q=lane&7).
// ---------------------------------------------------------------------------
__global__ __launch_bounds__(256) void aggr2_k(const int* __restrict__ rp,
                                               const int* __restrict__ csrc,
                                               const float* __restrict__ a_s,
                                               const float* __restrict__ a_d,
                                               const unsigned char* __restrict__ h8,
                                               const float* __restrict__ bias,
                                               float* __restrict__ out) {
    int lane = threadIdx.x & 63;
    int d = blockIdx.x * 4 + (threadIdx.x >> 6);
    if (d >= N_NODES) return;
    int j = lane >> 3;   // edge slot 0..7
    int q = lane & 7;    // channel octet: channels 8q..8q+7

    float ed = a_d[d];
    f32x4 accA = {0.f, 0.f, 0.f, 0.f}, accB = {0.f, 0.f, 0.f, 0.f};
    float den = 0.f;

    if (j == 0) {  // self loop: 8 lanes x int2 = 64B row
        float e0 = a_s[d] + ed;
        e0 = e0 > 0.f ? e0 : NEG_SLOPE * e0;
        float w0 = __expf(e0);
        den = w0;
        int2 u = *(const int2*)(h8 + (size_t)d * 64 + 8 * q);
        acc4(accA, w0, u.x); acc4(accB, w0, u.y);
    }

    int beg = rp[d], end = rp[d + 1];
    int s1_cur = 0, s2_cur = 0;
    if (beg < end) {
        int e1 = beg + j;
        int e2 = beg + 8 + j;
        s1_cur = csrc[e1 < end ? e1 : end - 1];
        s2_cur = csrc[e2 < end ? e2 : end - 1];
    }
    for (int cbeg = beg; cbeg < end; cbeg += 16) {
        int s1 = s1_cur, s2 = s2_cur;
        if (cbeg + 16 < end) {
            int e1 = cbeg + 16 + j;
            int e2 = cbeg + 24 + j;
            s1_cur = csrc[e1 < end ? e1 : end - 1];
            s2_cur = csrc[e2 < end ? e2 : end - 1];
        }
        // all four gathers depend only on s1/s2 -> issue together
        int2 u1 = *(const int2*)(h8 + (size_t)s1 * 64 + 8 * q);
        int2 u2 = *(const int2*)(h8 + (size_t)s2 * 64 + 8 * q);
        float as1 = a_s[s1];
        float as2 = a_s[s2];
        float es1 = as1 + ed;
        es1 = es1 > 0.f ? es1 : NEG_SLOPE * es1;
        float w1 = (cbeg + j < end) ? __expf(es1) : 0.f;
        float es2 = as2 + ed;
        es2 = es2 > 0.f ? es2 : NEG_SLOPE * es2;
        float w2 = (cbeg + 8 + j < end) ? __expf(es2) : 0.f;
        den += w1 + w2;
        acc4(accA, w1, u1.x); acc4(accB, w1, u1.y);
        acc4(accA, w2, u2.x); acc4(accB, w2, u2.y);
    }

    // reduce across edge-slot lanes (bits 3,4,5)
#pragma unroll
    for (int o = 8; o < 64; o <<= 1) {
        den += __shfl_xor(den, o, 64);
#pragma unroll
        for (int i = 0; i < 4; i++) {
            accA[i] += __shfl_xor(accA[i], o, 64);
            accB[i] += __shfl_xor(accB[i], o, 64);
        }
    }
    float inv = 1.f / (den + 1e-16f);

    const float4* bp = (const float4*)bias;
    float4 b0 = bp[2 * q], b1 = bp[2 * q + 1];
    float z[8];
    z[0] = fmaf(accA[0], inv, b0.x); z[1] = fmaf(accA[1], inv, b0.y);
    z[2] = fmaf(accA[2], inv, b0.z); z[3] = fmaf(accA[3], inv, b0.w);
    z[4] = fmaf(accB[0], inv, b1.x); z[5] = fmaf(accB[1], inv, b1.y);
    z[6] = fmaf(accB[2], inv, b1.z); z[7] = fmaf(accB[3], inv, b1.w);

    float m = z[0];
#pragma unroll
    for (int i = 1; i < 8; i++) m = fmaxf(m, z[i]);
#pragma unroll
    for (int o = 1; o < 8; o <<= 1) m = fmaxf(m, __shfl_xor(m, o, 64));
    float p = 0.f;
#pragma unroll
    for (int i = 0; i < 8; i++) p += __expf(z[i] - m);
#pragma unroll
    for (int o = 1; o < 8; o <<= 1) p += __shfl_xor(p, o, 64);
    float lse = m + logf(p);

    if (j == 0) {
        float4 o0 = {z[0] - lse, z[1] - lse, z[2] - lse, z[3] - lse};
        float4 o1 = {z[4] - lse, z[5] - lse, z[6] - lse, z[7] - lse};
        float4* op = (float4*)(out + (size_t)d * 64 + 8 * q);
        op[0] = o0;
        op[1] = o1;
    }
}

// ---------------------------------------------------------------------------
extern "C" void kernel_launch(void* const* d_in, const int* in_sizes, int n_in,
                              void* d_out, int out_size, void* d_ws, size_t ws_size,
                              hipStream_t stream) {
    const float* x   = (const float*)d_in[0];
    const void*  ei  = d_in[1];
    const float* W1  = (const float*)d_in[2];
    const float* as1 = (const float*)d_in[3];
    const float* ad1 = (const float*)d_in[4];
    const float* b1  = (const float*)d_in[5];
    const float* W2  = (const float*)d_in[6];
    const float* as2 = (const float*)d_in[7];
    const float* ad2 = (const float*)d_in[8];
    const float* b2  = (const float*)d_in[9];
    float* out = (float*)d_out;

    // workspace layout
    f16*   h1   = (f16*)d_ws;                             // N*128 f16 (reused as h2)
    f16*   out1 = h1 + (size_t)N_NODES * 128;             // N*128 f16
    unsigned char* h8 = (unsigned char*)(out1 + (size_t)N_NODES * 128);  // N*128 B
    f16*   w1f  = (f16*)(h8 + (size_t)N_NODES * 128);     // 16384 f16
    f16*   w2f  = w1f + 16384;                            // 8192 f16
    float* a_s  = (float*)(w2f + 8192);                   // N*8 f32
    float* a_d  = a_s + (size_t)N_NODES * 8;              // N*8 f32
    int*   rp   = (int*)(a_d + (size_t)N_NODES * 8);      // N+1 (+pad to 64)
    int*   bh   = rp + (N_NODES + 64);                    // NSCAN
    int*   bsum = bh + NSCAN;                             // 256
    int*   csrc = bsum + 256;                             // E
    int*   be   = csrc + N_EDGES;                         // E packed (src<<7|dlocal)
    f16*   h2   = h1;

    // --- CSR build: LDS-atomic bucket counting sort (no global atomics) ---
    bhist_k<<<B1, 256, 0, stream>>>(ei, bh);
    scan1_k<<<SCAN_NB, SCAN_BLK, 0, stream>>>(bh, bh, bsum, NSCAN);
    scan2_k<<<1, 256, 0, stream>>>(bsum, SCAN_NB);
    bscatter_k<<<B1, 256, 0, stream>>>(ei, bh, bsum, be);
    bcsr_k<<<NBUCK, 256, 0, stream>>>(bh, bsum, be, rp, csrc);

    // --- weight fragment prep ---
    cvt_wfrag_k<8><<<(4 * 8 * 512 + 255) / 256, 256, 0, stream>>>(W1, w1f);
    cvt_wfrag_k<4><<<(4 * 4 * 512 + 255) / 256, 256, 0, stream>>>(W2, w2f);

    // --- layer 1 ---
    gemm_mfma<8, float><<<(N_NODES + 63) / 64, 256, 0, stream>>>(x, w1f, h1, N_NODES);
    att_scores<8, 16><<<(N_NODES * 8 + 255) / 256, 256, 0, stream>>>(h1, as1, ad1, a_s, a_d, h8, N_NODES);
    aggr1_k<<<(N_NODES + 3) / 4, 256, 0, stream>>>(rp, csrc, a_s, a_d, h8, b1, out1);

    // --- layer 2 (fused bias + log_softmax) ---
    gemm_mfma<4, f16><<<(N_NODES + 63) / 64, 256, 0, stream>>>(out1, w2f, h2, N_NODES);
    att_scores<1, 64><<<(N_NODES + 255) / 256, 256, 0, stream>>>(h2, as2, ad2, a_s, a_d, h8, N_NODES);
    aggr2_k<<<(N_NODES + 3) / 4, 256, 0, stream>>>(rp, csrc, a_s, a_d, h8, b2, out);
}

// Round 18
// 202.640 us; speedup vs baseline: 1.0705x; 1.0705x over previous
//
#include <hip/hip_runtime.h>
#include <hip/hip_bf16.h>

#define N_NODES 100000
#define N_EDGES 1600000
#define NEG_SLOPE 0.2f

// --- bucket sort geometry ---
#define BUCK_SHIFT 7
#define NBUCK ((N_NODES + 127) >> BUCK_SHIFT)     // 782 buckets of 128 nodes
#define B1 256                                    // blocks in hist/scatter stages
#define CHUNK ((N_EDGES + B1 - 1) / B1)           // 6250 edges per block chunk

// --- generic scan geometry (for NBUCK*B1 = 200192 elements) ---
#define SCAN_ITEMS 4
#define SCAN_BLK 256
#define SCAN_CHUNK (SCAN_BLK * SCAN_ITEMS)        // 1024
#define NSCAN (NBUCK * B1)                        // 200192
#define SCAN_NB ((NSCAN + SCAN_CHUNK - 1) / SCAN_CHUNK)  // 196

typedef _Float16 f16;
typedef _Float16 f16x8 __attribute__((ext_vector_type(8)));
typedef _Float16 f16x2 __attribute__((ext_vector_type(2)));
typedef float f32x4 __attribute__((ext_vector_type(4)));
typedef float f32x2v __attribute__((ext_vector_type(2)));

// ---------------------------------------------------------------------------
// Edge dtype probe (int64 reference vs possible int32 delivery)
// ---------------------------------------------------------------------------
__device__ __forceinline__ bool edges_are_i64(const void* p) {
    const unsigned long long* q = (const unsigned long long*)p;
    bool ok = true;
#pragma unroll
    for (int i = 0; i < 8; i++)
        if (q[i] >= (unsigned long long)N_NODES) ok = false;
    return ok;
}
__device__ __forceinline__ int edge_src(const void* ei, int j, bool i64) {
    return i64 ? (int)((const long long*)ei)[j] : ((const int*)ei)[j];
}
__device__ __forceinline__ int edge_dst(const void* ei, int j, bool i64) {
    return i64 ? (int)((const long long*)ei)[N_EDGES + j] : ((const int*)ei)[N_EDGES + j];
}

// fp8 quad accumulate: 4 fp8 channels from one int, weighted into f32x4
__device__ __forceinline__ void acc4(f32x4& a, float w, int u) {
    f32x2v p0 = __builtin_amdgcn_cvt_pk_f32_fp8(u, false);
    f32x2v p1 = __builtin_amdgcn_cvt_pk_f32_fp8(u, true);
    a[0] = fmaf(w, p0[0], a[0]);
    a[1] = fmaf(w, p0[1], a[1]);
    a[2] = fmaf(w, p1[0], a[2]);
    a[3] = fmaf(w, p1[1], a[3]);
}

// ---------------------------------------------------------------------------
// CSR stage 1: per-(bucket, block) histogram via LDS atomics only.
// ---------------------------------------------------------------------------
__global__ __launch_bounds__(256) void bhist_k(const void* __restrict__ ei,
                                               int* __restrict__ bh) {
    __shared__ int hist[NBUCK];
    bool i64 = edges_are_i64(ei);
    int bl = blockIdx.x, t = threadIdx.x;
    for (int i = t; i < NBUCK; i += 256) hist[i] = 0;
    __syncthreads();
    int lo = bl * CHUNK, hi = min(lo + CHUNK, N_EDGES);
    for (int j = lo + t; j < hi; j += 256)
        atomicAdd(&hist[edge_dst(ei, j, i64) >> BUCK_SHIFT], 1);
    __syncthreads();
    for (int i = t; i < NBUCK; i += 256) bh[i * B1 + bl] = hist[i];
}

// ---------------------------------------------------------------------------
// Generic exclusive scan, n elements. Block sums left UNAPPLIED (consumers
// add bsum[idx / SCAN_CHUNK] themselves -- saves the scan3 pass).
// ---------------------------------------------------------------------------
__global__ __launch_bounds__(SCAN_BLK) void scan1_k(const int* __restrict__ in,
                                                    int* __restrict__ outp,
                                                    int* __restrict__ bsum, int n) {
    __shared__ int lds[SCAN_BLK];
    int t = threadIdx.x, b = blockIdx.x;
    int base = b * SCAN_CHUNK + t * SCAN_ITEMS;
    int v[SCAN_ITEMS];
    int s = 0;
#pragma unroll
    for (int i = 0; i < SCAN_ITEMS; i++) {
        v[i] = (base + i < n) ? in[base + i] : 0;
        s += v[i];
    }
    lds[t] = s;
    __syncthreads();
    for (int o = 1; o < SCAN_BLK; o <<= 1) {
        int x = (t >= o) ? lds[t - o] : 0;
        __syncthreads();
        lds[t] += x;
        __syncthreads();
    }
    if (t == SCAN_BLK - 1) bsum[b] = lds[t];
    int run = lds[t] - s;
#pragma unroll
    for (int i = 0; i < SCAN_ITEMS; i++) {
        if (base + i < n) outp[base + i] = run;
        run += v[i];
    }
}

__global__ __launch_bounds__(256) void scan2_k(int* __restrict__ bsum, int nb) {
    __shared__ int lds[256];
    int t = threadIdx.x;
    int v = (t < nb) ? bsum[t] : 0;
    lds[t] = v;
    __syncthreads();
    for (int o = 1; o < 256; o <<= 1) {
        int x = (t >= o) ? lds[t - o] : 0;
        __syncthreads();
        lds[t] += x;
        __syncthreads();
    }
    if (t < nb) bsum[t] = lds[t] - v;
}

// ---------------------------------------------------------------------------
// CSR stage 2: scatter edges into bucket-grouped packed (src<<7 | dlocal).
// Cursor init folds in the block-sum (fused scan3).
// ---------------------------------------------------------------------------
__global__ __launch_bounds__(256) void bscatter_k(const void* __restrict__ ei,
                                                  const int* __restrict__ bh,
                                                  const int* __restrict__ bsum,
                                                  int* __restrict__ be) {
    __shared__ int cur[NBUCK];
    bool i64 = edges_are_i64(ei);
    int bl = blockIdx.x, t = threadIdx.x;
    for (int i = t; i < NBUCK; i += 256) {
        int idx = i * B1 + bl;
        cur[i] = bh[idx] + bsum[idx / SCAN_CHUNK];
    }
    __syncthreads();
    int lo = bl * CHUNK, hi = min(lo + CHUNK, N_EDGES);
    for (int j = lo + t; j < hi; j += 256) {
        int d = edge_dst(ei, j, i64);
        int sr = edge_src(ei, j, i64);
        int pos = atomicAdd(&cur[d >> BUCK_SHIFT], 1);
        be[pos] = (sr << BUCK_SHIFT) | (d & 127);
    }
}

// ---------------------------------------------------------------------------
// CSR stage 3: one block per bucket -> rp + csrc. No global atomics.
// ---------------------------------------------------------------------------
__global__ __launch_bounds__(256) void bcsr_k(const int* __restrict__ bh,
                                              const int* __restrict__ bsum,
                                              const int* __restrict__ be,
                                              int* __restrict__ rp,
                                              int* __restrict__ csrc) {
    __shared__ int cnt[128];
    __shared__ int pre[128];
    int b = blockIdx.x, t = threadIdx.x;
    int bi = b * B1;
    int beg = bh[bi] + bsum[bi / SCAN_CHUNK];
    int end = N_EDGES;
    if (b != NBUCK - 1) {
        int bj = (b + 1) * B1;
        end = bh[bj] + bsum[bj / SCAN_CHUNK];
    }
    if (t < 128) cnt[t] = 0;
    __syncthreads();
    for (int j = beg + t; j < end; j += 256)
        atomicAdd(&cnt[be[j] & 127], 1);
    __syncthreads();
    if (t < 128) pre[t] = cnt[t];
    __syncthreads();
    for (int o = 1; o < 128; o <<= 1) {
        int x = 0;
        if (t < 128 && t >= o) x = pre[t - o];
        __syncthreads();
        if (t < 128) pre[t] += x;
        __syncthreads();
    }
    if (t < 128) {
        int node = (b << BUCK_SHIFT) + t;
        int excl = pre[t] - cnt[t];
        if (node < N_NODES) rp[node] = beg + excl;
        cnt[t] = excl;
    }
    if (b == 0 && t == 0) rp[N_NODES] = N_EDGES;
    __syncthreads();
    for (int j = beg + t; j < end; j += 256) {
        int e = be[j];
        int pos = beg + atomicAdd(&cnt[e & 127], 1);
        csrc[pos] = e >> BUCK_SHIFT;
    }
}

// ---------------------------------------------------------------------------
// Pre-shuffle W1[128x128] and W2[128x64] into MFMA B-fragment order
// (single fused launch; W1 occupies idx [0,16384), W2 idx [16384,24576)).
// ---------------------------------------------------------------------------
__global__ void cvt_wfrag2_k(const float* __restrict__ W1, const float* __restrict__ W2,
                             f16* __restrict__ w1f, f16* __restrict__ w2f) {
    int idx = blockIdx.x * blockDim.x + threadIdx.x;
    const float* W;
    f16* wf;
    int NCT, li;
    if (idx < 16384) { W = W1; wf = w1f; NCT = 8; li = idx; }
    else if (idx < 24576) { W = W2; wf = w2f; NCT = 4; li = idx - 16384; }
    else return;
    int j = li & 7;
    int lane = (li >> 3) & 63;
    int ct = (li >> 9) % NCT;
    int ks = (li >> 9) / NCT;
    int k = ks * 32 + 8 * (lane >> 4) + j;
    int col = ct * 16 + (lane & 15);
    wf[li] = (f16)W[k * (NCT * 16) + col];
}

// ---------------------------------------------------------------------------
// MFMA GEMM: H[n x NCT*16] = A[n x 128] @ W. 4 waves x 16 rows per block.
// ---------------------------------------------------------------------------
template <int NCT, typename AT>
__global__ __launch_bounds__(256) void gemm_mfma(const AT* __restrict__ A,
                                                 const f16* __restrict__ wf,
                                                 f16* __restrict__ H, int n) {
    int lane = threadIdx.x & 63;
    int row0 = blockIdx.x * 64 + (threadIdx.x >> 6) * 16;
    int m = lane & 15, g = lane >> 4;
    f32x4 acc[NCT];
#pragma unroll
    for (int ct = 0; ct < NCT; ct++) acc[ct] = (f32x4){0.f, 0.f, 0.f, 0.f};

    int ar = row0 + m;
    if (ar >= n) ar = 0;
    const AT* arow = A + (size_t)ar * 128 + g * 8;
    const f16x8* bp = (const f16x8*)wf;
#pragma unroll
    for (int ks = 0; ks < 4; ks++) {
        f16x8 af;
        if constexpr (sizeof(AT) == 4) {
            const float4* p = (const float4*)(arow + ks * 32);
            float4 a = p[0], b = p[1];
            af[0] = (f16)a.x; af[1] = (f16)a.y; af[2] = (f16)a.z; af[3] = (f16)a.w;
            af[4] = (f16)b.x; af[5] = (f16)b.y; af[6] = (f16)b.z; af[7] = (f16)b.w;
        } else {
            af = *(const f16x8*)(arow + ks * 32);
        }
#pragma unroll
        for (int ct = 0; ct < NCT; ct++) {
            f16x8 bf = bp[(ks * NCT + ct) * 64 + lane];
            acc[ct] = __builtin_amdgcn_mfma_f32_16x16x32_f16(af, bf, acc[ct], 0, 0, 0);
        }
    }
#pragma unroll
    for (int ct = 0; ct < NCT; ct++)
#pragma unroll
        for (int r = 0; r < 4; r++) {
            int orow = row0 + g * 4 + r;
            if (orow < n) H[(size_t)orow * (NCT * 16) + ct * 16 + m] = (f16)acc[ct][r];
        }
}

// ---------------------------------------------------------------------------
// Per-node attention half-scores + fp8(e4m3) encode of the feature rows.
// ---------------------------------------------------------------------------
template <int HEADS, int CH>
__global__ void att_scores(const f16* __restrict__ H, const float* __restrict__ att_s,
                           const float* __restrict__ att_d, float* __restrict__ a_s,
                           float* __restrict__ a_d, unsigned char* __restrict__ h8,
                           int n) {
    int idx = blockIdx.x * blockDim.x + threadIdx.x;
    if (idx >= n * HEADS) return;
    int node = idx / HEADS;
    int h = idx - node * HEADS;
    const f16x8* hp = (const f16x8*)(H + (size_t)node * (HEADS * CH) + h * CH);
    float vals[CH];
    float s = 0.f, d = 0.f;
#pragma unroll
    for (int c8 = 0; c8 < CH / 8; c8++) {
        f16x8 v = hp[c8];
#pragma unroll
        for (int j = 0; j < 8; j++) {
            float x = (float)v[j];
            vals[c8 * 8 + j] = x;
            s = fmaf(x, att_s[h * CH + c8 * 8 + j], s);
            d = fmaf(x, att_d[h * CH + c8 * 8 + j], d);
        }
    }
    a_s[idx] = s;
    a_d[idx] = d;

    int4* dst = (int4*)(h8 + (size_t)node * (HEADS * CH) + h * CH);
#pragma unroll
    for (int t = 0; t < CH / 16; t++) {
        int w[4];
#pragma unroll
        for (int q = 0; q < 4; q++) {
            int u = __builtin_amdgcn_cvt_pk_fp8_f32(vals[t * 16 + 4 * q],
                                                    vals[t * 16 + 4 * q + 1], 0, false);
            u = __builtin_amdgcn_cvt_pk_fp8_f32(vals[t * 16 + 4 * q + 2],
                                                vals[t * 16 + 4 * q + 3], u, true);
            w[q] = u;
        }
        dst[t] = make_int4(w[0], w[1], w[2], w[3]);
    }
}

// ---------------------------------------------------------------------------
// Layer 1 fused aggregation, software-pipelined, 8-edge chunks (R16 proven):
//   - chunk k+1's csrc preloaded during chunk k
//   - all 8 h8 gathers issue (readlane addresses) before the score exp.
// Lane roles: phase 1 (eidx=lane&7, head=lane>>3) one exp/lane;
// phase 2 weight via static ds_swizzle src=(l&0x38)|K, channels [2l,2l+1].
// ---------------------------------------------------------------------------
__global__ __launch_bounds__(256) void aggr1_k(const int* __restrict__ rp,
                                               const int* __restrict__ csrc,
                                               const float* __restrict__ a_s,
                                               const float* __restrict__ a_d,
                                               const unsigned char* __restrict__ h8,
                                               const float* __restrict__ bias,
                                               f16* __restrict__ out) {
    int lane = threadIdx.x & 63;
    int d = blockIdx.x * 4 + (threadIdx.x >> 6);
    if (d >= N_NODES) return;
    int head = lane >> 3;   // head for score AND value phases
    int eidx = lane & 7;    // phase-1 edge slot

    float ed = a_d[d * 8 + head];

    // self loop
    float e0 = a_s[d * 8 + head] + ed;
    e0 = e0 > 0.f ? e0 : NEG_SLOPE * e0;
    float w0 = __expf(e0);
    unsigned short u0 = *(const unsigned short*)(h8 + (size_t)d * 128 + 2 * lane);
    f32x2v v0 = __builtin_amdgcn_cvt_pk_f32_fp8((int)u0, false);
    float den = w0, nx = w0 * v0[0], ny = w0 * v0[1];

    int beg = rp[d], end = rp[d + 1];
    int s_cur = 0;
    if (beg < end) {
        int e = beg + eidx;
        s_cur = csrc[e < end ? e : end - 1];
    }
    for (int cbeg = beg; cbeg < end; cbeg += 8) {
        int s = s_cur;
        // prefetch next chunk's csrc (wave-uniform branch)
        if (cbeg + 8 < end) {
            int e = cbeg + 8 + eidx;
            s_cur = csrc[e < end ? e : end - 1];
        }
        // issue all 8 h8 gathers first (addresses = readlane of s)
        unsigned short uu0, uu1, uu2, uu3, uu4, uu5, uu6, uu7;
#define A1_LOAD(K)                                                                        \
        {                                                                                 \
            int se = __builtin_amdgcn_readlane(s, K);                                     \
            uu##K = *(const unsigned short*)(h8 + (size_t)se * 128 + 2 * lane);           \
        }
        A1_LOAD(0) A1_LOAD(1) A1_LOAD(2) A1_LOAD(3)
        A1_LOAD(4) A1_LOAD(5) A1_LOAD(6) A1_LOAD(7)
#undef A1_LOAD
        // score gather (issued alongside the h8 gathers), then exp
        float as = a_s[s * 8 + head];
        float es = as + ed;
        es = es > 0.f ? es : NEG_SLOPE * es;
        float w = (cbeg + eidx < end) ? __expf(es) : 0.f;
        // consume
#define A1_USE(K)                                                                         \
        {                                                                                 \
            float we = __int_as_float(__builtin_amdgcn_ds_swizzle(                         \
                __float_as_int(w), ((K) << 5) | 0x18));                                   \
            f32x2v v = __builtin_amdgcn_cvt_pk_f32_fp8((int)uu##K, false);                \
            den += we;                                                                    \
            nx = fmaf(we, v[0], nx);                                                      \
            ny = fmaf(we, v[1], ny);                                                      \
        }
        A1_USE(0) A1_USE(1) A1_USE(2) A1_USE(3)
        A1_USE(4) A1_USE(5) A1_USE(6) A1_USE(7)
#undef A1_USE
    }
    float inv = 1.f / (den + 1e-16f);
    float2 b = ((const float2*)bias)[lane];
    f16x2 r;
    r[0] = (f16)fmaxf(fmaf(nx, inv, b.x), 0.f);
    r[1] = (f16)fmaxf(fmaf(ny, inv, b.y), 0.f);
    ((f16x2*)out)[(size_t)d * 64 + lane] = r;
}

// ---------------------------------------------------------------------------
// Layer 2 fused aggregation + bias + log_softmax, software-pipelined,
// 8-edge chunks. lane = (edge slot j=lane>>3, channel octet q=lane&7).
// ---------------------------------------------------------------------------
__global__ __launch_bounds__(256) void aggr2_k(const int* __restrict__ rp,
                                               const int* __restrict__ csrc,
                                               const float* __restrict__ a_s,
                                               const float* __restrict__ a_d,
                                               const unsigned char* __restrict__ h8,
                                               const float* __restrict__ bias,
                                               float* __restrict__ out) {
    int lane = threadIdx.x & 63;
    int d = blockIdx.x * 4 + (threadIdx.x >> 6);
    if (d >= N_NODES) return;
    int j = lane >> 3;   // edge slot 0..7
    int q = lane & 7;    // channel octet: channels 8q..8q+7

    float ed = a_d[d];
    f32x4 accA = {0.f, 0.f, 0.f, 0.f}, accB = {0.f, 0.f, 0.f, 0.f};
    float den = 0.f;

    if (j == 0) {  // self loop: 8 lanes x int2 = 64B row
        float e0 = a_s[d] + ed;
        e0 = e0 > 0.f ? e0 : NEG_SLOPE * e0;
        float w0 = __expf(e0);
        den = w0;
        int2 u = *(const int2*)(h8 + (size_t)d * 64 + 8 * q);
        acc4(accA, w0, u.x); acc4(accB, w0, u.y);
    }

    int beg = rp[d], end = rp[d + 1];
    int s_cur = 0;
    if (beg < end) {
        int e = beg + j;
        s_cur = csrc[e < end ? e : end - 1];
    }
    for (int cbeg = beg; cbeg < end; cbeg += 8) {
        int s = s_cur;
        if (cbeg + 8 < end) {
            int e = cbeg + 8 + j;
            s_cur = csrc[e < end ? e : end - 1];
        }
        // both gathers depend only on s -> issue together
        int2 u = *(const int2*)(h8 + (size_t)s * 64 + 8 * q);
        float as = a_s[s];
        float es = as + ed;
        es = es > 0.f ? es : NEG_SLOPE * es;
        float w = (cbeg + j < end) ? __expf(es) : 0.f;
        den += w;
        acc4(accA, w, u.x); acc4(accB, w, u.y);
    }

    // reduce across edge-slot lanes (bits 3,4,5)
#pragma unroll
    for (int o = 8; o < 64; o <<= 1) {
        den += __shfl_xor(den, o, 64);
#pragma unroll
        for (int i = 0; i < 4; i++) {
            accA[i] += __shfl_xor(accA[i], o, 64);
            accB[i] += __shfl_xor(accB[i], o, 64);
        }
    }
    float inv = 1.f / (den + 1e-16f);

    const float4* bp = (const float4*)bias;
    float4 b0 = bp[2 * q], b1 = bp[2 * q + 1];
    float z[8];
    z[0] = fmaf(accA[0], inv, b0.x); z[1] = fmaf(accA[1], inv, b0.y);
    z[2] = fmaf(accA[2], inv, b0.z); z[3] = fmaf(accA[3], inv, b0.w);
    z[4] = fmaf(accB[0], inv, b1.x); z[5] = fmaf(accB[1], inv, b1.y);
    z[6] = fmaf(accB[2], inv, b1.z); z[7] = fmaf(accB[3], inv, b1.w);

    float m = z[0];
#pragma unroll
    for (int i = 1; i < 8; i++) m = fmaxf(m, z[i]);
#pragma unroll
    for (int o = 1; o < 8; o <<= 1) m = fmaxf(m, __shfl_xor(m, o, 64));
    float p = 0.f;
#pragma unroll
    for (int i = 0; i < 8; i++) p += __expf(z[i] - m);
#pragma unroll
    for (int o = 1; o < 8; o <<= 1) p += __shfl_xor(p, o, 64);
    float lse = m + logf(p);

    if (j == 0) {
        float4 o0 = {z[0] - lse, z[1] - lse, z[2] - lse, z[3] - lse};
        float4 o1 = {z[4] - lse, z[5] - lse, z[6] - lse, z[7] - lse};
        float4* op = (float4*)(out + (size_t)d * 64 + 8 * q);
        op[0] = o0;
        op[1] = o1;
    }
}

// ---------------------------------------------------------------------------
extern "C" void kernel_launch(void* const* d_in, const int* in_sizes, int n_in,
                              void* d_out, int out_size, void* d_ws, size_t ws_size,
                              hipStream_t stream) {
    const float* x   = (const float*)d_in[0];
    const void*  ei  = d_in[1];
    const float* W1  = (const float*)d_in[2];
    const float* as1 = (const float*)d_in[3];
    const float* ad1 = (const float*)d_in[4];
    const float* b1  = (const float*)d_in[5];
    const float* W2  = (const float*)d_in[6];
    const float* as2 = (const float*)d_in[7];
    const float* ad2 = (const float*)d_in[8];
    const float* b2  = (const float*)d_in[9];
    float* out = (float*)d_out;

    // workspace layout
    f16*   h1   = (f16*)d_ws;                             // N*128 f16 (reused as h2)
    f16*   out1 = h1 + (size_t)N_NODES * 128;             // N*128 f16
    unsigned char* h8 = (unsigned char*)(out1 + (size_t)N_NODES * 128);  // N*128 B
    f16*   w1f  = (f16*)(h8 + (size_t)N_NODES * 128);     // 16384 f16
    f16*   w2f  = w1f + 16384;                            // 8192 f16
    float* a_s  = (float*)(w2f + 8192);                   // N*8 f32
    float* a_d  = a_s + (size_t)N_NODES * 8;              // N*8 f32
    int*   rp   = (int*)(a_d + (size_t)N_NODES * 8);      // N+1 (+pad to 64)
    int*   bh   = rp + (N_NODES + 64);                    // NSCAN
    int*   bsum = bh + NSCAN;                             // 256
    int*   csrc = bsum + 256;                             // E
    int*   be   = csrc + N_EDGES;                         // E packed (src<<7|dlocal)
    f16*   h2   = h1;

    // --- CSR build: LDS-atomic bucket counting sort (no global atomics) ---
    bhist_k<<<B1, 256, 0, stream>>>(ei, bh);
    scan1_k<<<SCAN_NB, SCAN_BLK, 0, stream>>>(bh, bh, bsum, NSCAN);
    scan2_k<<<1, 256, 0, stream>>>(bsum, SCAN_NB);
    bscatter_k<<<B1, 256, 0, stream>>>(ei, bh, bsum, be);
    bcsr_k<<<NBUCK, 256, 0, stream>>>(bh, bsum, be, rp, csrc);

    // --- weight fragment prep (single fused launch) ---
    cvt_wfrag2_k<<<(24576 + 255) / 256, 256, 0, stream>>>(W1, W2, w1f, w2f);

    // --- layer 1 ---
    gemm_mfma<8, float><<<(N_NODES + 63) / 64, 256, 0, stream>>>(x, w1f, h1, N_NODES);
    att_scores<8, 16><<<(N_NODES * 8 + 255) / 256, 256, 0, stream>>>(h1, as1, ad1, a_s, a_d, h8, N_NODES);
    aggr1_k<<<(N_NODES + 3) / 4, 256, 0, stream>>>(rp, csrc, a_s, a_d, h8, b1, out1);

    // --- layer 2 (fused bias + log_softmax) ---
    gemm_mfma<4, f16><<<(N_NODES + 63) / 64, 256, 0, stream>>>(out1, w2f, h2, N_NODES);
    att_scores<1, 64><<<(N_NODES + 255) / 256, 256, 0, stream>>>(h2, as2, ad2, a_s, a_d, h8, N_NODES);
    aggr2_k<<<(N_NODES + 3) / 4, 256, 0, stream>>>(rp, csrc, a_s, a_d, h8, b2, out);
}